// Round 15
// baseline (80.976 us; speedup 1.0000x reference)
//
#include <hip/hip_runtime.h>

typedef __attribute__((ext_vector_type(8))) short bf16x8;   // 8 bf16 in 4 VGPRs
typedef __attribute__((ext_vector_type(8))) unsigned short u16x8;
typedef __attribute__((ext_vector_type(4))) float f32x4;

#define GLDS16(SRC, DST) __builtin_amdgcn_global_load_lds( \
    (const __attribute__((address_space(1))) void*)(SRC),  \
    (__attribute__((address_space(3))) void*)(DST), 16, 0, 0)

__device__ __forceinline__ unsigned short f2bf(float f) {
  unsigned int u = __float_as_uint(f);
  u += 0x7FFFu + ((u >> 16) & 1u);       // RNE
  return (unsigned short)(u >> 16);
}
__device__ __forceinline__ float bf2f(unsigned short u) {
  return __uint_as_float((unsigned int)u << 16);
}

// ---------------- fused fp32 -> bf16 converts + bias concat -----------------
// Q weights/bias pre-scaled by (1/8)*log2(e): scores land in log2 domain so
// softmax uses bare v_exp_f32 (exp2) with no per-element mul.
#define QSCL 0.1803368801111f    // 0.125 * log2(e)
__global__ void cvt_all(const float* __restrict__ hid,
                        const float* __restrict__ Wq, const float* __restrict__ Wk,
                        const float* __restrict__ Wv, const float* __restrict__ Wo,
                        const float* __restrict__ bq, const float* __restrict__ bk,
                        const float* __restrict__ bv,
                        unsigned short* __restrict__ hb, unsigned short* __restrict__ Wcat,
                        unsigned short* __restrict__ Wob, float* __restrict__ bcat) {
  const int H4 = 2048 * 1024 / 4, W4 = 1024 * 1024 / 4;
  int i = blockIdx.x * 256 + threadIdx.x;
  const float* src; unsigned short* dst; float scale = 1.0f; int j;
  if (i < H4)                { src = hid; dst = hb;                 j = i; }
  else if (i < H4 + W4)      { src = Wq;  dst = Wcat;               j = i - H4; scale = QSCL; }
  else if (i < H4 + 2 * W4)  { src = Wk;  dst = Wcat + 1024 * 1024; j = i - H4 - W4; }
  else if (i < H4 + 3 * W4)  { src = Wv;  dst = Wcat + 2048 * 1024; j = i - H4 - 2 * W4; }
  else if (i < H4 + 4 * W4)  { src = Wo;  dst = Wob;                j = i - H4 - 3 * W4; }
  else {                                           // bias concat, fp32 out
    j = i - H4 - 4 * W4;                           // 0..767 float4s -> bcat[3072]
    int e = j * 4;
    const float* b = (e < 1024) ? bq : (e < 2048 ? bk + (-1024) : bv + (-2048));
    float4 v = *(const float4*)(b + e);
    if (e < 1024) { v.x *= QSCL; v.y *= QSCL; v.z *= QSCL; v.w *= QSCL; }
    ((float4*)bcat)[j] = v;
    return;
  }
  float4 v = ((const float4*)src)[j];
  ushort4 o;
  o.x = f2bf(v.x * scale); o.y = f2bf(v.y * scale);
  o.z = f2bf(v.z * scale); o.w = f2bf(v.w * scale);
  ((ushort4*)dst)[j] = o;
}

// ---------------- C = A * B^T + bias ; A[M,K] bf16, B[N,K] bf16 -----------
// m97 2-barrier structure, BK=64, XOR-swizzled LDS (rule #21: inverse-swizzled
// GLDS source + swizzled ds_read). 4 waves 2x2, wave tile (BM/2)x(BN/2).
template <int BM, int BN, typename OutT>
__global__ __launch_bounds__(256) void gemm_bt(
    const unsigned short* __restrict__ A, const unsigned short* __restrict__ B,
    const float* __restrict__ bias, OutT* __restrict__ C,
    int M, int N, int K, int lda, int ldb, int ldc)
{
  constexpr int MREP = BM / 32, NREP = BN / 32;
  constexpr int AI = BM / 32, BI = BN / 32;        // GLDS16 instrs per K-tile
  __shared__ __align__(16) unsigned short As[2][BM * 64];
  __shared__ __align__(16) unsigned short Bs[2][BN * 64];
  const int t = threadIdx.x;
  const int lane = t & 63;
  const int w = t >> 6;
  const int wm = w >> 1, wn = w & 1;
  const int lr = lane & 15, lk = lane >> 4;
  const int tm = blockIdx.y * BM, tn = blockIdx.x * BN;

  f32x4 acc[MREP][NREP];
#pragma unroll
  for (int m = 0; m < MREP; ++m)
#pragma unroll
    for (int n = 0; n < NREP; ++n) acc[m][n] = (f32x4){0.f, 0.f, 0.f, 0.f};

  // staging: instr i covers rows i*32+(t>>3); 8 elems at swizzled source col
  const int srow = t >> 3;                              // 0..31
  const int scol = ((t & 7) ^ (srow & 7)) << 3;         // inverse-swizzled col
  const int ldsb = (t & 192) * 8;                       // wave-uniform base

  const int NT = K >> 6;
#pragma unroll
  for (int i = 0; i < AI; ++i)
    GLDS16(A + (size_t)(tm + i * 32 + srow) * lda + scol, &As[0][i * 2048 + ldsb]);
#pragma unroll
  for (int i = 0; i < BI; ++i)
    GLDS16(B + (size_t)(tn + i * 32 + srow) * ldb + scol, &Bs[0][i * 2048 + ldsb]);
  __syncthreads();

  for (int kt = 0; kt < NT; ++kt) {
    const int cur = kt & 1, nxt = cur ^ 1;
    if (kt + 1 < NT) {
      const int k0 = (kt + 1) << 6;
#pragma unroll
      for (int i = 0; i < AI; ++i)
        GLDS16(A + (size_t)(tm + i * 32 + srow) * lda + k0 + scol, &As[nxt][i * 2048 + ldsb]);
#pragma unroll
      for (int i = 0; i < BI; ++i)
        GLDS16(B + (size_t)(tn + i * 32 + srow) * ldb + k0 + scol, &Bs[nxt][i * 2048 + ldsb]);
    }
    bf16x8 af[MREP][2], bfv[NREP][2];
#pragma unroll
    for (int m = 0; m < MREP; ++m) {
      const int ra = wm * (BM / 2) + m * 16 + lr, r7 = ra & 7;
      af[m][0] = *(const bf16x8*)&As[cur][ra * 64 + ((lk ^ r7) << 3)];
      af[m][1] = *(const bf16x8*)&As[cur][ra * 64 + (((4 + lk) ^ r7) << 3)];
    }
#pragma unroll
    for (int n = 0; n < NREP; ++n) {
      const int rb = wn * (BN / 2) + n * 16 + lr, r7 = rb & 7;
      bfv[n][0] = *(const bf16x8*)&Bs[cur][rb * 64 + ((lk ^ r7) << 3)];
      bfv[n][1] = *(const bf16x8*)&Bs[cur][rb * 64 + (((4 + lk) ^ r7) << 3)];
    }
#pragma unroll
    for (int kk = 0; kk < 2; ++kk)
#pragma unroll
      for (int m = 0; m < MREP; ++m)
#pragma unroll
        for (int n = 0; n < NREP; ++n)
          acc[m][n] = __builtin_amdgcn_mfma_f32_16x16x32_bf16(af[m][kk], bfv[n][kk], acc[m][n], 0, 0, 0);
    __syncthreads();
  }

  // epilogue: C/D layout col=lane&15, row=(lane>>4)*4+reg  [m89]
#pragma unroll
  for (int m = 0; m < MREP; ++m) {
    const int row0 = tm + wm * (BM / 2) + m * 16 + lk * 4;
#pragma unroll
    for (int n = 0; n < NREP; ++n) {
      const int col = tn + wn * (BN / 2) + n * 16 + lr;
      const float bb = bias ? bias[col] : 0.f;
#pragma unroll
      for (int r = 0; r < 4; ++r) {
        float v = acc[m][n][r] + bb;
        if constexpr (sizeof(OutT) == 2) {
          ((unsigned short*)C)[(size_t)(row0 + r) * ldc + col] = f2bf(v);
        } else {
          ((float*)C)[(size_t)(row0 + r) * ldc + col] = v;
        }
      }
    }
  }
}

// ---------------- causal flash attention, KV-split (flash-decoding) ---------
// Round-9 proven structure + defer-max (T13; THR in log2 units) + setprio (T5)
// + exp2-domain softmax (scores pre-scaled by log2(e) via QSCL).
__device__ __forceinline__ int slot_off(int qt) {    // cum. chunks for qt>=8
  int g = qt >> 3;
  return (g == 1) ? (qt - 8) * 2 : (g == 2) ? 16 + (qt - 16) * 3 : 40 + (qt - 24) * 4;
}

__global__ __launch_bounds__(256) void attn_fwd(const unsigned short* __restrict__ QKV,
                                                unsigned short* __restrict__ ctx,
                                                unsigned short* __restrict__ Opart,
                                                float* __restrict__ mlbuf)
{
  __shared__ __align__(16) unsigned short Ks[64 * 64];
  __shared__ __align__(16) unsigned short Vt[64 * 64];
  __shared__ __align__(16) unsigned int   Pl[4][16 * 36];   // P^T packed u32, stride 36

  const int t = threadIdx.x;
  const int lane = t & 63, w = t >> 6;
  const int lr = lane & 15, lk = lane >> 4;
  const int h = blockIdx.y;
  // pair decode; reversed so heavy (8-tile) chunks launch first
  const int p = 79 - (int)blockIdx.x;
  int qt, c;
  if (p < 8)       { qt = p; c = 0; }
  else if (p < 24) { qt = 8 + ((p - 8) >> 1); c = (p - 8) & 1; }
  else if (p < 48) { int r = p - 24; qt = 16 + r / 3; c = r - (r / 3) * 3; }
  else             { int r = p - 48; qt = 24 + (r >> 2); c = r & 3; }
  const int nc = (qt >> 3) + 1;
  const int q0 = qt * 64;
  const size_t ldq = 3072;

  // Q as B-operand frags: lane holds Q[q0+w*16+lr][slice*32 + lk*8 + i]
  const unsigned short* qbase = QKV + (size_t)(q0 + w * 16 + lr) * ldq + h * 64;
  const bf16x8 qf0 = *(const bf16x8*)(qbase + lk * 8);
  const bf16x8 qf1 = *(const bf16x8*)(qbase + 32 + lk * 8);

  f32x4 acc[4];   // O^T: rows d = dsub*16 + lk*4 + r, col q = lr
#pragma unroll
  for (int d = 0; d < 4; ++d) acc[d] = (f32x4){0.f, 0.f, 0.f, 0.f};
  float mrun = -__builtin_inff(), lrun = 0.f;

  const int srow0 = t >> 3;           // kv row 0..31
  const int srow1 = 32 + (t >> 3);    // kv row 32..63
  const int sslot = t & 7;            // 16B slot within 128B row

  const unsigned short* kbase = QKV + 1024 + h * 64;
  const unsigned short* vbase = QKV + 2048 + h * 64;

  const int kt0 = c * 8;
  const int kt1 = (qt < kt0 + 7) ? qt : kt0 + 7;
  for (int kt = kt0; kt <= kt1; ++kt) {
    const int kv0 = kt * 64;
    __syncthreads();   // prior tile fully consumed before overwrite
    // --- stage K (linear LDS dest, inverse-swizzled global source) ---
    {
      const int c0 = (sslot ^ (srow0 & 7)) << 3;
      const int c1 = (sslot ^ (srow1 & 7)) << 3;
      GLDS16(kbase + (size_t)(kv0 + srow0) * ldq + c0, &Ks[(t & 192) * 8]);
      GLDS16(kbase + (size_t)(kv0 + srow1) * ldq + c1, &Ks[(256 + (t & 192)) * 8]);
    }
    // --- stage V transposed with slot swizzle ---
    {
      const bf16x8 v0 = *(const bf16x8*)(vbase + (size_t)(kv0 + srow0) * ldq + (sslot << 3));
      const bf16x8 v1 = *(const bf16x8*)(vbase + (size_t)(kv0 + srow1) * ldq + (sslot << 3));
      const int d0 = sslot << 3;
#pragma unroll
      for (int j = 0; j < 8; ++j) {
        const int d = d0 + j;
        const int key = (d ^ (d >> 3)) & 7;
        Vt[d * 64 + (((srow0 >> 3) ^ key) << 3) + (srow0 & 7)] = (unsigned short)v0[j];
        Vt[d * 64 + (((srow1 >> 3) ^ key) << 3) + (srow1 & 7)] = (unsigned short)v1[j];
      }
    }
    __syncthreads();   // staging visible (drains vmcnt+lgkm)

    // --- S^T = K Q^T : 4 kv-subtiles x 2 d-slices; D[kv][q], q = lr ---
    f32x4 sacc[4];
    __builtin_amdgcn_s_setprio(1);
#pragma unroll
    for (int sub = 0; sub < 4; ++sub) {
      const int krow = sub * 16 + lr;
      const int sw = krow & 7;
      const bf16x8 kf0 = *(const bf16x8*)&Ks[krow * 64 + ((lk ^ sw) << 3)];
      const bf16x8 kf1 = *(const bf16x8*)&Ks[krow * 64 + (((4 + lk) ^ sw) << 3)];
      f32x4 s = (f32x4){0.f, 0.f, 0.f, 0.f};
      s = __builtin_amdgcn_mfma_f32_16x16x32_bf16(kf0, qf0, s, 0, 0, 0);
      s = __builtin_amdgcn_mfma_f32_16x16x32_bf16(kf1, qf1, s, 0, 0, 0);
      sacc[sub] = s;
    }
    __builtin_amdgcn_s_setprio(0);

    // --- causal mask (diagonal tile only): kv_local > q_local -> -inf ---
    if (kt == qt) {
      const int qg = w * 16 + lr;
#pragma unroll
      for (int sub = 0; sub < 4; ++sub) {
#pragma unroll
        for (int r = 0; r < 4; ++r)
          if (sub * 16 + lk * 4 + r > qg) sacc[sub][r] = -__builtin_inff();
      }
    }

    // --- online softmax in log2 domain; defer-max (T13, THR=8*log2e) ---
    float pm = -__builtin_inff();
#pragma unroll
    for (int sub = 0; sub < 4; ++sub)
#pragma unroll
      for (int r = 0; r < 4; ++r) pm = fmaxf(pm, sacc[sub][r]);
    pm = fmaxf(pm, __shfl_xor(pm, 16, 64));
    pm = fmaxf(pm, __shfl_xor(pm, 32, 64));
    if (!__all(pm <= mrun + 11.5416f)) {
      const float mnew = fmaxf(mrun, pm);
      const float sc = exp2f(mrun - mnew);   // 0 on first tile
      lrun *= sc;
#pragma unroll
      for (int d = 0; d < 4; ++d) acc[d] *= sc;
      mrun = mnew;
    }
    float pp[4][4]; float rs = 0.f;
#pragma unroll
    for (int sub = 0; sub < 4; ++sub)
#pragma unroll
      for (int r = 0; r < 4; ++r) { pp[sub][r] = exp2f(sacc[sub][r] - mrun); rs += pp[sub][r]; }
    rs += __shfl_xor(rs, 16, 64);
    rs += __shfl_xor(rs, 32, 64);
    lrun += rs;

    // --- pack P^T to bf16 pairs, write per-wave LDS ---
    unsigned int* prow = &Pl[w][lr * 36];
#pragma unroll
    for (int sub = 0; sub < 4; ++sub) {
#pragma unroll
      for (int j = 0; j < 2; ++j) {
        unsigned int pk;
        asm("v_cvt_pk_bf16_f32 %0, %1, %2" : "=v"(pk) : "v"(pp[sub][2 * j]), "v"(pp[sub][2 * j + 1]));
        prow[sub * 8 + lk * 2 + j] = pk;
      }
    }
    asm volatile("s_waitcnt lgkmcnt(0)" ::: "memory");   // rule #18 fence
    __builtin_amdgcn_sched_barrier(0);

    // --- O^T += V^T P^T : A from swizzled Vt, B = P^T (16B-aligned b128) ---
    const bf16x8 pb0 = *(const bf16x8*)&Pl[w][lr * 36 + lk * 4];
    const bf16x8 pb1 = *(const bf16x8*)&Pl[w][lr * 36 + 16 + lk * 4];
    __builtin_amdgcn_s_setprio(1);
#pragma unroll
    for (int dsub = 0; dsub < 4; ++dsub) {
      const int dd = dsub * 16 + lr;
      const int key = (dd ^ (dd >> 3)) & 7;
      const bf16x8 bv0 = *(const bf16x8*)&Vt[dd * 64 + ((lk ^ key) << 3)];
      const bf16x8 bv1 = *(const bf16x8*)&Vt[dd * 64 + (((4 + lk) ^ key) << 3)];
      acc[dsub] = __builtin_amdgcn_mfma_f32_16x16x32_bf16(bv0, pb0, acc[dsub], 0, 0, 0);
      acc[dsub] = __builtin_amdgcn_mfma_f32_16x16x32_bf16(bv1, pb1, acc[dsub], 0, 0, 0);
    }
    __builtin_amdgcn_s_setprio(0);
  }

  if (nc == 1) {
    // --- direct: ctx[q][h*64 + d] = O^T[d][q] / l ; 8B packed stores ---
    const float inv = 1.0f / lrun;
#pragma unroll
    for (int dsub = 0; dsub < 4; ++dsub) {
      ushort4 o;
      o.x = f2bf(acc[dsub][0] * inv);
      o.y = f2bf(acc[dsub][1] * inv);
      o.z = f2bf(acc[dsub][2] * inv);
      o.w = f2bf(acc[dsub][3] * inv);
      *(ushort4*)&ctx[(size_t)(q0 + w * 16 + lr) * 1024 + h * 64 + dsub * 16 + lk * 4] = o;
    }
  } else {
    // --- partial: Opart[slot][q][d] (bf16, unnormalized), ml[slot][q] f32x2 ---
    const int slot = h * 72 + slot_off(qt) + c;
    unsigned short* Op = Opart + (size_t)slot * 4096;
    const int ql = w * 16 + lr;
#pragma unroll
    for (int dsub = 0; dsub < 4; ++dsub) {
      ushort4 o;
      o.x = f2bf(acc[dsub][0]);
      o.y = f2bf(acc[dsub][1]);
      o.z = f2bf(acc[dsub][2]);
      o.w = f2bf(acc[dsub][3]);
      *(ushort4*)&Op[ql * 64 + dsub * 16 + lk * 4] = o;
    }
    if (lk == 0)
      *(float2*)&mlbuf[(slot * 64 + ql) * 2] = make_float2(mrun, lrun);
  }
}

// ---------------- combine partials -> ctx (log2-domain weights) -------------
template <int NC>
__device__ __forceinline__ void combine_body(const unsigned short* __restrict__ Opart,
                                             const float* __restrict__ mlbuf,
                                             unsigned short* __restrict__ ctx,
                                             int qt, int half, int h, int t) {
  const int q = half * 32 + (t >> 3);      // q row within tile
  const int d0 = (t & 7) * 8;              // 8 contiguous d per thread
  const int slot0 = h * 72 + slot_off(qt);
  float m[NC], l[NC];
#pragma unroll
  for (int c = 0; c < NC; ++c) {
    const float2 ml = *(const float2*)&mlbuf[((slot0 + c) * 64 + q) * 2];
    m[c] = ml.x; l[c] = ml.y;
  }
  float M = m[0];
#pragma unroll
  for (int c = 1; c < NC; ++c) M = fmaxf(M, m[c]);
  float wgt[NC], L = 0.f;
#pragma unroll
  for (int c = 0; c < NC; ++c) { wgt[c] = exp2f(m[c] - M); L += wgt[c] * l[c]; }
  u16x8 v[NC];
#pragma unroll
  for (int c = 0; c < NC; ++c)
    v[c] = *(const u16x8*)&Opart[(size_t)(slot0 + c) * 4096 + q * 64 + d0];
  const float inv = 1.0f / L;
  u16x8 r;
#pragma unroll
  for (int j = 0; j < 8; ++j) {
    float o = 0.f;
#pragma unroll
    for (int c = 0; c < NC; ++c) o += wgt[c] * bf2f(v[c][j]);
    r[j] = f2bf(o * inv);
  }
  *(u16x8*)&ctx[(size_t)(qt * 64 + q) * 1024 + h * 64 + d0] = r;
}

__global__ __launch_bounds__(256) void attn_combine(const unsigned short* __restrict__ Opart,
                                                    const float* __restrict__ mlbuf,
                                                    unsigned short* __restrict__ ctx) {
  const int t = threadIdx.x;
  const int h = blockIdx.y;
  const int idx = blockIdx.x;        // 0..47
  const int g = idx >> 4;            // qt group: 0 -> nc2, 1 -> nc3, 2 -> nc4
  const int i = idx & 15;
  const int qt = 8 + g * 8 + (i >> 1);
  const int half = i & 1;
  if (g == 0)      combine_body<2>(Opart, mlbuf, ctx, qt, half, h, t);
  else if (g == 1) combine_body<3>(Opart, mlbuf, ctx, qt, half, h, t);
  else             combine_body<4>(Opart, mlbuf, ctx, qt, half, h, t);
}

// ---------------------------------------------------------------------------
extern "C" void kernel_launch(void* const* d_in, const int* in_sizes, int n_in,
                              void* d_out, int out_size, void* d_ws, size_t ws_size,
                              hipStream_t stream) {
  const float* hid = (const float*)d_in[0];
  const float* Wq  = (const float*)d_in[1];
  const float* bq  = (const float*)d_in[2];
  const float* Wk  = (const float*)d_in[3];
  const float* bk  = (const float*)d_in[4];
  const float* Wv  = (const float*)d_in[5];
  const float* bv  = (const float*)d_in[6];
  const float* Wo  = (const float*)d_in[7];
  const float* bo  = (const float*)d_in[8];
  float* out = (float*)d_out;

  char* ws = (char*)d_ws;
  unsigned short* hb   = (unsigned short*)(ws);                 //  4 MB  hidden bf16
  unsigned short* Wcat = (unsigned short*)(ws + (4u  << 20));   //  6 MB  Wq|Wk|Wv bf16
  unsigned short* Wob  = (unsigned short*)(ws + (10u << 20));   //  2 MB  Wo bf16
  float*          bcat = (float*)         (ws + (12u << 20));   // 12 KB  bq*QSCL|bk|bv
  unsigned short* QKV  = (unsigned short*)(ws + (13u << 20));   // 12 MB
  unsigned short* ctx  = (unsigned short*)(ws + (25u << 20));   //  4 MB
  // attn partials ALIAS hb/Wcat (dead after gemm1): 9 MB + 0.6 MB < 10 MB
  unsigned short* Opart = (unsigned short*)(ws);                // 1152 x 8 KB
  float*          mlbuf = (float*)(ws + 9437184);               // 1152 x 512 B

  // fused converts: hidden, Wq(*QSCL), Wk, Wv, Wo, bias concat  (6147 blocks)
  cvt_all<<<6147, 256, 0, stream>>>(hid, Wq, Wk, Wv, Wo, bq, bk, bv,
                                    hb, Wcat, Wob, bcat);

  // QKV = hb @ Wcat^T + bcat   [2048 x 3072]  (BM=64,BN=128 -> 768 blocks)
  gemm_bt<64, 128, unsigned short><<<dim3(24, 32), 256, 0, stream>>>(
      hb, Wcat, bcat, QKV, 2048, 3072, 1024, 1024, 1024, 3072);

  // causal flash attention, KV-split -> ctx + partials  (1280 blocks)
  attn_fwd<<<dim3(80, 16), 256, 0, stream>>>(QKV, ctx, Opart, mlbuf);

  // merge partials for qt >= 8  (768 blocks, vectorized)
  attn_combine<<<dim3(48, 16), 256, 0, stream>>>(Opart, mlbuf, ctx);

  // out = ctx @ Wo^T + bo   [2048 x 1024] fp32  (BM=64,BN=64 -> 512 blocks)
  gemm_bt<64, 64, float><<<dim3(16, 32), 256, 0, stream>>>(
      ctx, Wob, bo, out, 2048, 1024, 1024, 1024, 1024, 1024);
}

// Round 16
// 77.790 us; speedup vs baseline: 1.0410x; 1.0410x over previous
//
#include <hip/hip_runtime.h>

typedef __attribute__((ext_vector_type(8))) short bf16x8;   // 8 bf16 in 4 VGPRs
typedef __attribute__((ext_vector_type(8))) unsigned short u16x8;
typedef __attribute__((ext_vector_type(4))) float f32x4;

#define GLDS16(SRC, DST) __builtin_amdgcn_global_load_lds( \
    (const __attribute__((address_space(1))) void*)(SRC),  \
    (__attribute__((address_space(3))) void*)(DST), 16, 0, 0)

__device__ __forceinline__ unsigned short f2bf(float f) {
  unsigned int u = __float_as_uint(f);
  u += 0x7FFFu + ((u >> 16) & 1u);       // RNE
  return (unsigned short)(u >> 16);
}
__device__ __forceinline__ float bf2f(unsigned short u) {
  return __uint_as_float((unsigned int)u << 16);
}

// ---------------- fused fp32 -> bf16 converts + bias concat -----------------
__global__ void cvt_all(const float* __restrict__ hid,
                        const float* __restrict__ Wq, const float* __restrict__ Wk,
                        const float* __restrict__ Wv, const float* __restrict__ Wo,
                        const float* __restrict__ bq, const float* __restrict__ bk,
                        const float* __restrict__ bv,
                        unsigned short* __restrict__ hb, unsigned short* __restrict__ Wcat,
                        unsigned short* __restrict__ Wob, float* __restrict__ bcat) {
  const int H4 = 2048 * 1024 / 4, W4 = 1024 * 1024 / 4;
  int i = blockIdx.x * 256 + threadIdx.x;
  const float* src; unsigned short* dst; float scale = 1.0f; int j;
  if (i < H4)                { src = hid; dst = hb;                 j = i; }
  else if (i < H4 + W4)      { src = Wq;  dst = Wcat;               j = i - H4; scale = 0.125f; }
  else if (i < H4 + 2 * W4)  { src = Wk;  dst = Wcat + 1024 * 1024; j = i - H4 - W4; }
  else if (i < H4 + 3 * W4)  { src = Wv;  dst = Wcat + 2048 * 1024; j = i - H4 - 2 * W4; }
  else if (i < H4 + 4 * W4)  { src = Wo;  dst = Wob;                j = i - H4 - 3 * W4; }
  else {                                           // bias concat, fp32 out
    j = i - H4 - 4 * W4;                           // 0..767 float4s -> bcat[3072]
    int e = j * 4;
    const float* b = (e < 1024) ? bq : (e < 2048 ? bk + (-1024) : bv + (-2048));
    float4 v = *(const float4*)(b + e);
    if (e < 1024) { v.x *= 0.125f; v.y *= 0.125f; v.z *= 0.125f; v.w *= 0.125f; }
    ((float4*)bcat)[j] = v;
    return;
  }
  float4 v = ((const float4*)src)[j];
  ushort4 o;
  o.x = f2bf(v.x * scale); o.y = f2bf(v.y * scale);
  o.z = f2bf(v.z * scale); o.w = f2bf(v.w * scale);
  ((ushort4*)dst)[j] = o;
}

// ---------------- C = A * B^T + bias ; A[M,K] bf16, B[N,K] bf16 -----------
// m97 2-barrier structure, BK=64, XOR-swizzled LDS (rule #21: inverse-swizzled
// GLDS source + swizzled ds_read). 4 waves 2x2, wave tile (BM/2)x(BN/2).
template <int BM, int BN, typename OutT>
__global__ __launch_bounds__(256) void gemm_bt(
    const unsigned short* __restrict__ A, const unsigned short* __restrict__ B,
    const float* __restrict__ bias, OutT* __restrict__ C,
    int M, int N, int K, int lda, int ldb, int ldc)
{
  constexpr int MREP = BM / 32, NREP = BN / 32;
  constexpr int AI = BM / 32, BI = BN / 32;        // GLDS16 instrs per K-tile
  __shared__ __align__(16) unsigned short As[2][BM * 64];
  __shared__ __align__(16) unsigned short Bs[2][BN * 64];
  const int t = threadIdx.x;
  const int lane = t & 63;
  const int w = t >> 6;
  const int wm = w >> 1, wn = w & 1;
  const int lr = lane & 15, lk = lane >> 4;
  const int tm = blockIdx.y * BM, tn = blockIdx.x * BN;

  f32x4 acc[MREP][NREP];
#pragma unroll
  for (int m = 0; m < MREP; ++m)
#pragma unroll
    for (int n = 0; n < NREP; ++n) acc[m][n] = (f32x4){0.f, 0.f, 0.f, 0.f};

  // staging: instr i covers rows i*32+(t>>3); 8 elems at swizzled source col
  const int srow = t >> 3;                              // 0..31
  const int scol = ((t & 7) ^ (srow & 7)) << 3;         // inverse-swizzled col
  const int ldsb = (t & 192) * 8;                       // wave-uniform base

  const int NT = K >> 6;
#pragma unroll
  for (int i = 0; i < AI; ++i)
    GLDS16(A + (size_t)(tm + i * 32 + srow) * lda + scol, &As[0][i * 2048 + ldsb]);
#pragma unroll
  for (int i = 0; i < BI; ++i)
    GLDS16(B + (size_t)(tn + i * 32 + srow) * ldb + scol, &Bs[0][i * 2048 + ldsb]);
  __syncthreads();

  for (int kt = 0; kt < NT; ++kt) {
    const int cur = kt & 1, nxt = cur ^ 1;
    if (kt + 1 < NT) {
      const int k0 = (kt + 1) << 6;
#pragma unroll
      for (int i = 0; i < AI; ++i)
        GLDS16(A + (size_t)(tm + i * 32 + srow) * lda + k0 + scol, &As[nxt][i * 2048 + ldsb]);
#pragma unroll
      for (int i = 0; i < BI; ++i)
        GLDS16(B + (size_t)(tn + i * 32 + srow) * ldb + k0 + scol, &Bs[nxt][i * 2048 + ldsb]);
    }
    bf16x8 af[MREP][2], bfv[NREP][2];
#pragma unroll
    for (int m = 0; m < MREP; ++m) {
      const int ra = wm * (BM / 2) + m * 16 + lr, r7 = ra & 7;
      af[m][0] = *(const bf16x8*)&As[cur][ra * 64 + ((lk ^ r7) << 3)];
      af[m][1] = *(const bf16x8*)&As[cur][ra * 64 + (((4 + lk) ^ r7) << 3)];
    }
#pragma unroll
    for (int n = 0; n < NREP; ++n) {
      const int rb = wn * (BN / 2) + n * 16 + lr, r7 = rb & 7;
      bfv[n][0] = *(const bf16x8*)&Bs[cur][rb * 64 + ((lk ^ r7) << 3)];
      bfv[n][1] = *(const bf16x8*)&Bs[cur][rb * 64 + (((4 + lk) ^ r7) << 3)];
    }
#pragma unroll
    for (int kk = 0; kk < 2; ++kk)
#pragma unroll
      for (int m = 0; m < MREP; ++m)
#pragma unroll
        for (int n = 0; n < NREP; ++n)
          acc[m][n] = __builtin_amdgcn_mfma_f32_16x16x32_bf16(af[m][kk], bfv[n][kk], acc[m][n], 0, 0, 0);
    __syncthreads();
  }

  // epilogue: C/D layout col=lane&15, row=(lane>>4)*4+reg  [m89]
#pragma unroll
  for (int m = 0; m < MREP; ++m) {
    const int row0 = tm + wm * (BM / 2) + m * 16 + lk * 4;
#pragma unroll
    for (int n = 0; n < NREP; ++n) {
      const int col = tn + wn * (BN / 2) + n * 16 + lr;
      const float bb = bias ? bias[col] : 0.f;
#pragma unroll
      for (int r = 0; r < 4; ++r) {
        float v = acc[m][n][r] + bb;
        if constexpr (sizeof(OutT) == 2) {
          ((unsigned short*)C)[(size_t)(row0 + r) * ldc + col] = f2bf(v);
        } else {
          ((float*)C)[(size_t)(row0 + r) * ldc + col] = v;
        }
      }
    }
  }
}

// ---------------- causal flash attention, KV-split (flash-decoding) ---------
// Round-9 proven structure + defer-max (T13, THR=8) + setprio (T5)
// + paired-kv V-transpose: packed u32 ds_writes (half the writes/extracts;
//   Vt LAYOUT AND READ PATH UNCHANGED - only writer mapping differs).
__device__ __forceinline__ int slot_off(int qt) {    // cum. chunks for qt>=8
  int g = qt >> 3;
  return (g == 1) ? (qt - 8) * 2 : (g == 2) ? 16 + (qt - 16) * 3 : 40 + (qt - 24) * 4;
}

__global__ __launch_bounds__(256) void attn_fwd(const unsigned short* __restrict__ QKV,
                                                unsigned short* __restrict__ ctx,
                                                unsigned short* __restrict__ Opart,
                                                float* __restrict__ mlbuf)
{
  __shared__ __align__(16) unsigned short Ks[64 * 64];
  __shared__ __align__(16) unsigned short Vt[64 * 64];
  __shared__ __align__(16) unsigned int   Pl[4][16 * 36];   // P^T packed u32, stride 36

  const int t = threadIdx.x;
  const int lane = t & 63, w = t >> 6;
  const int lr = lane & 15, lk = lane >> 4;
  const int h = blockIdx.y;
  // pair decode; reversed so heavy (8-tile) chunks launch first
  const int p = 79 - (int)blockIdx.x;
  int qt, c;
  if (p < 8)       { qt = p; c = 0; }
  else if (p < 24) { qt = 8 + ((p - 8) >> 1); c = (p - 8) & 1; }
  else if (p < 48) { int r = p - 24; qt = 16 + r / 3; c = r - (r / 3) * 3; }
  else             { int r = p - 48; qt = 24 + (r >> 2); c = r & 3; }
  const int nc = (qt >> 3) + 1;
  const int q0 = qt * 64;
  const size_t ldq = 3072;

  // Q as B-operand frags: lane holds Q[q0+w*16+lr][slice*32 + lk*8 + i]
  const unsigned short* qbase = QKV + (size_t)(q0 + w * 16 + lr) * ldq + h * 64;
  const bf16x8 qf0 = *(const bf16x8*)(qbase + lk * 8);
  const bf16x8 qf1 = *(const bf16x8*)(qbase + 32 + lk * 8);

  f32x4 acc[4];   // O^T: rows d = dsub*16 + lk*4 + r, col q = lr
#pragma unroll
  for (int d = 0; d < 4; ++d) acc[d] = (f32x4){0.f, 0.f, 0.f, 0.f};
  float mrun = -__builtin_inff(), lrun = 0.f;

  const int srow0 = t >> 3;           // K kv row 0..31
  const int srow1 = 32 + (t >> 3);    // K kv row 32..63
  const int sslot = t & 7;            // 16B slot within 128B row
  const int vr = (t >> 3) << 1;       // V kv row pair base: 0,2,...,62

  const unsigned short* kbase = QKV + 1024 + h * 64;
  const unsigned short* vbase = QKV + 2048 + h * 64;

  const int kt0 = c * 8;
  const int kt1 = (qt < kt0 + 7) ? qt : kt0 + 7;
  for (int kt = kt0; kt <= kt1; ++kt) {
    const int kv0 = kt * 64;
    __syncthreads();   // prior tile fully consumed before overwrite
    // --- stage K (linear LDS dest, inverse-swizzled global source) ---
    {
      const int c0 = (sslot ^ (srow0 & 7)) << 3;
      const int c1 = (sslot ^ (srow1 & 7)) << 3;
      GLDS16(kbase + (size_t)(kv0 + srow0) * ldq + c0, &Ks[(t & 192) * 8]);
      GLDS16(kbase + (size_t)(kv0 + srow1) * ldq + c1, &Ks[(256 + (t & 192)) * 8]);
    }
    // --- stage V transposed: adjacent-kv pairs packed into u32 writes ---
    // (kv, kv+1) for same d share the (kv>>3)^key slot (kv&7 even), so they
    // are contiguous in Vt -> one ds_write_b32. Layout identical to before.
    {
      const bf16x8 v0 = *(const bf16x8*)(vbase + (size_t)(kv0 + vr) * ldq + (sslot << 3));
      const bf16x8 v1 = *(const bf16x8*)(vbase + (size_t)(kv0 + vr + 1) * ldq + (sslot << 3));
      const int d0 = sslot << 3;
      const int g8 = vr >> 3, r7 = vr & 7;        // r7 even
#pragma unroll
      for (int j = 0; j < 8; ++j) {
        const int d = d0 + j;
        const int key = (d ^ (d >> 3)) & 7;
        const unsigned int pk = (unsigned int)(unsigned short)v0[j]
                              | ((unsigned int)(unsigned short)v1[j] << 16);
        *(unsigned int*)&Vt[d * 64 + ((g8 ^ key) << 3) + r7] = pk;
      }
    }
    __syncthreads();   // staging visible (drains vmcnt+lgkm)

    // --- S^T = K Q^T : 4 kv-subtiles x 2 d-slices; D[kv][q], q = lr ---
    f32x4 sacc[4];
    __builtin_amdgcn_s_setprio(1);
#pragma unroll
    for (int sub = 0; sub < 4; ++sub) {
      const int krow = sub * 16 + lr;
      const int sw = krow & 7;
      const bf16x8 kf0 = *(const bf16x8*)&Ks[krow * 64 + ((lk ^ sw) << 3)];
      const bf16x8 kf1 = *(const bf16x8*)&Ks[krow * 64 + (((4 + lk) ^ sw) << 3)];
      f32x4 s = (f32x4){0.f, 0.f, 0.f, 0.f};
      s = __builtin_amdgcn_mfma_f32_16x16x32_bf16(kf0, qf0, s, 0, 0, 0);
      s = __builtin_amdgcn_mfma_f32_16x16x32_bf16(kf1, qf1, s, 0, 0, 0);
      sacc[sub] = s;
    }
    __builtin_amdgcn_s_setprio(0);

    // --- causal mask (diagonal tile only): kv_local > q_local -> -inf ---
    if (kt == qt) {
      const int qg = w * 16 + lr;
#pragma unroll
      for (int sub = 0; sub < 4; ++sub) {
#pragma unroll
        for (int r = 0; r < 4; ++r)
          if (sub * 16 + lk * 4 + r > qg) sacc[sub][r] = -__builtin_inff();
      }
    }

    // --- online softmax, in-register; defer-max (T13, THR=8) ---
    float pm = -__builtin_inff();
#pragma unroll
    for (int sub = 0; sub < 4; ++sub)
#pragma unroll
      for (int r = 0; r < 4; ++r) pm = fmaxf(pm, sacc[sub][r]);
    pm = fmaxf(pm, __shfl_xor(pm, 16, 64));
    pm = fmaxf(pm, __shfl_xor(pm, 32, 64));
    if (!__all(pm <= mrun + 8.0f)) {
      const float mnew = fmaxf(mrun, pm);
      const float sc = __expf(mrun - mnew);   // 0 on first tile
      lrun *= sc;
#pragma unroll
      for (int d = 0; d < 4; ++d) acc[d] *= sc;
      mrun = mnew;
    }
    float pp[4][4]; float rs = 0.f;
#pragma unroll
    for (int sub = 0; sub < 4; ++sub)
#pragma unroll
      for (int r = 0; r < 4; ++r) { pp[sub][r] = __expf(sacc[sub][r] - mrun); rs += pp[sub][r]; }
    rs += __shfl_xor(rs, 16, 64);
    rs += __shfl_xor(rs, 32, 64);
    lrun += rs;

    // --- pack P^T to bf16 pairs, write per-wave LDS ---
    unsigned int* prow = &Pl[w][lr * 36];
#pragma unroll
    for (int sub = 0; sub < 4; ++sub) {
#pragma unroll
      for (int j = 0; j < 2; ++j) {
        unsigned int pk;
        asm("v_cvt_pk_bf16_f32 %0, %1, %2" : "=v"(pk) : "v"(pp[sub][2 * j]), "v"(pp[sub][2 * j + 1]));
        prow[sub * 8 + lk * 2 + j] = pk;
      }
    }
    asm volatile("s_waitcnt lgkmcnt(0)" ::: "memory");   // rule #18 fence
    __builtin_amdgcn_sched_barrier(0);

    // --- O^T += V^T P^T : A from swizzled Vt, B = P^T (16B-aligned b128) ---
    const bf16x8 pb0 = *(const bf16x8*)&Pl[w][lr * 36 + lk * 4];
    const bf16x8 pb1 = *(const bf16x8*)&Pl[w][lr * 36 + 16 + lk * 4];
    __builtin_amdgcn_s_setprio(1);
#pragma unroll
    for (int dsub = 0; dsub < 4; ++dsub) {
      const int dd = dsub * 16 + lr;
      const int key = (dd ^ (dd >> 3)) & 7;
      const bf16x8 bv0 = *(const bf16x8*)&Vt[dd * 64 + ((lk ^ key) << 3)];
      const bf16x8 bv1 = *(const bf16x8*)&Vt[dd * 64 + (((4 + lk) ^ key) << 3)];
      acc[dsub] = __builtin_amdgcn_mfma_f32_16x16x32_bf16(bv0, pb0, acc[dsub], 0, 0, 0);
      acc[dsub] = __builtin_amdgcn_mfma_f32_16x16x32_bf16(bv1, pb1, acc[dsub], 0, 0, 0);
    }
    __builtin_amdgcn_s_setprio(0);
  }

  if (nc == 1) {
    // --- direct: ctx[q][h*64 + d] = O^T[d][q] / l ; 8B packed stores ---
    const float inv = 1.0f / lrun;
#pragma unroll
    for (int dsub = 0; dsub < 4; ++dsub) {
      ushort4 o;
      o.x = f2bf(acc[dsub][0] * inv);
      o.y = f2bf(acc[dsub][1] * inv);
      o.z = f2bf(acc[dsub][2] * inv);
      o.w = f2bf(acc[dsub][3] * inv);
      *(ushort4*)&ctx[(size_t)(q0 + w * 16 + lr) * 1024 + h * 64 + dsub * 16 + lk * 4] = o;
    }
  } else {
    // --- partial: Opart[slot][q][d] (bf16, unnormalized), ml[slot][q] f32x2 ---
    const int slot = h * 72 + slot_off(qt) + c;
    unsigned short* Op = Opart + (size_t)slot * 4096;
    const int ql = w * 16 + lr;
#pragma unroll
    for (int dsub = 0; dsub < 4; ++dsub) {
      ushort4 o;
      o.x = f2bf(acc[dsub][0]);
      o.y = f2bf(acc[dsub][1]);
      o.z = f2bf(acc[dsub][2]);
      o.w = f2bf(acc[dsub][3]);
      *(ushort4*)&Op[ql * 64 + dsub * 16 + lk * 4] = o;
    }
    if (lk == 0)
      *(float2*)&mlbuf[(slot * 64 + ql) * 2] = make_float2(mrun, lrun);
  }
}

// ---------------- combine partials -> ctx (vectorized, NC unrolled) ---------
template <int NC>
__device__ __forceinline__ void combine_body(const unsigned short* __restrict__ Opart,
                                             const float* __restrict__ mlbuf,
                                             unsigned short* __restrict__ ctx,
                                             int qt, int half, int h, int t) {
  const int q = half * 32 + (t >> 3);      // q row within tile
  const int d0 = (t & 7) * 8;              // 8 contiguous d per thread
  const int slot0 = h * 72 + slot_off(qt);
  float m[NC], l[NC];
#pragma unroll
  for (int c = 0; c < NC; ++c) {
    const float2 ml = *(const float2*)&mlbuf[((slot0 + c) * 64 + q) * 2];
    m[c] = ml.x; l[c] = ml.y;
  }
  float M = m[0];
#pragma unroll
  for (int c = 1; c < NC; ++c) M = fmaxf(M, m[c]);
  float wgt[NC], L = 0.f;
#pragma unroll
  for (int c = 0; c < NC; ++c) { wgt[c] = __expf(m[c] - M); L += wgt[c] * l[c]; }
  u16x8 v[NC];
#pragma unroll
  for (int c = 0; c < NC; ++c)
    v[c] = *(const u16x8*)&Opart[(size_t)(slot0 + c) * 4096 + q * 64 + d0];
  const float inv = 1.0f / L;
  u16x8 r;
#pragma unroll
  for (int j = 0; j < 8; ++j) {
    float o = 0.f;
#pragma unroll
    for (int c = 0; c < NC; ++c) o += wgt[c] * bf2f(v[c][j]);
    r[j] = f2bf(o * inv);
  }
  *(u16x8*)&ctx[(size_t)(qt * 64 + q) * 1024 + h * 64 + d0] = r;
}

__global__ __launch_bounds__(256) void attn_combine(const unsigned short* __restrict__ Opart,
                                                    const float* __restrict__ mlbuf,
                                                    unsigned short* __restrict__ ctx) {
  const int t = threadIdx.x;
  const int h = blockIdx.y;
  const int idx = blockIdx.x;        // 0..47
  const int g = idx >> 4;            // qt group: 0 -> nc2, 1 -> nc3, 2 -> nc4
  const int i = idx & 15;
  const int qt = 8 + g * 8 + (i >> 1);
  const int half = i & 1;
  if (g == 0)      combine_body<2>(Opart, mlbuf, ctx, qt, half, h, t);
  else if (g == 1) combine_body<3>(Opart, mlbuf, ctx, qt, half, h, t);
  else             combine_body<4>(Opart, mlbuf, ctx, qt, half, h, t);
}

// ---------------------------------------------------------------------------
extern "C" void kernel_launch(void* const* d_in, const int* in_sizes, int n_in,
                              void* d_out, int out_size, void* d_ws, size_t ws_size,
                              hipStream_t stream) {
  const float* hid = (const float*)d_in[0];
  const float* Wq  = (const float*)d_in[1];
  const float* bq  = (const float*)d_in[2];
  const float* Wk  = (const float*)d_in[3];
  const float* bk  = (const float*)d_in[4];
  const float* Wv  = (const float*)d_in[5];
  const float* bv  = (const float*)d_in[6];
  const float* Wo  = (const float*)d_in[7];
  const float* bo  = (const float*)d_in[8];
  float* out = (float*)d_out;

  char* ws = (char*)d_ws;
  unsigned short* hb   = (unsigned short*)(ws);                 //  4 MB  hidden bf16
  unsigned short* Wcat = (unsigned short*)(ws + (4u  << 20));   //  6 MB  Wq|Wk|Wv bf16
  unsigned short* Wob  = (unsigned short*)(ws + (10u << 20));   //  2 MB  Wo bf16
  float*          bcat = (float*)         (ws + (12u << 20));   // 12 KB  bq/8|bk|bv
  unsigned short* QKV  = (unsigned short*)(ws + (13u << 20));   // 12 MB
  unsigned short* ctx  = (unsigned short*)(ws + (25u << 20));   //  4 MB
  // attn partials ALIAS hb/Wcat (dead after gemm1): 9 MB + 0.6 MB < 10 MB
  unsigned short* Opart = (unsigned short*)(ws);                // 1152 x 8 KB
  float*          mlbuf = (float*)(ws + 9437184);               // 1152 x 512 B

  // fused converts: hidden, Wq(*1/8), Wk, Wv, Wo, bias concat  (6147 blocks)
  cvt_all<<<6147, 256, 0, stream>>>(hid, Wq, Wk, Wv, Wo, bq, bk, bv,
                                    hb, Wcat, Wob, bcat);

  // QKV = hb @ Wcat^T + bcat   [2048 x 3072]  (BM=64,BN=128 -> 768 blocks)
  gemm_bt<64, 128, unsigned short><<<dim3(24, 32), 256, 0, stream>>>(
      hb, Wcat, bcat, QKV, 2048, 3072, 1024, 1024, 1024, 3072);

  // causal flash attention, KV-split -> ctx + partials  (1280 blocks)
  attn_fwd<<<dim3(80, 16), 256, 0, stream>>>(QKV, ctx, Opart, mlbuf);

  // merge partials for qt >= 8  (768 blocks, vectorized)
  attn_combine<<<dim3(48, 16), 256, 0, stream>>>(Opart, mlbuf, ctx);

  // out = ctx @ Wo^T + bo   [2048 x 1024] fp32  (BM=64,BN=64 -> 512 blocks)
  gemm_bt<64, 64, float><<<dim3(16, 32), 256, 0, stream>>>(
      ctx, Wob, bo, out, 2048, 1024, 1024, 1024, 1024, 1024);
}